// Round 6
// baseline (1468.833 us; speedup 1.0000x reference)
//
#include <hip/hip_runtime.h>

// RationalQuadratic: 4-layer MLP conditioner (bf16 MFMA GEMMs) + RQ spline.
// R6: GEMM restructure — B (weights, 2-3 MB, L2-hot) no longer staged via
// LDS; fragments loaded straight from global into VGPRs. Removes half the
// LDS round-trip (R5 model: LDS read BW 2-3x MFMA cycles -> MfmaUtil 28%).
// A stays on the global_load_lds path (streamed, read by 2 waves each).
// Also: adaptive chunking (C=1/2/4 by ws_size; R5 learned ws < ~344 MB so
// C=4 was silently active since R3 — fewer chunks = fewer launch gaps).

typedef __bf16 bf16_t;
typedef __bf16 bf16x8 __attribute__((ext_vector_type(8)));
typedef float f32x4 __attribute__((ext_vector_type(4)));

#define GLOAD_LDS16(g, l)                                               \
  __builtin_amdgcn_global_load_lds(                                     \
      (const __attribute__((address_space(1))) void*)(g),               \
      (__attribute__((address_space(3))) void*)(l), 16, 0, 0)

// ---------------------------------------------------------------------------
// W (K,N) fp32 row-major -> Wt (Npad,K) bf16 row-major. grid (K/64, Npad/64).
__global__ __launch_bounds__(256) void transpose_w(
    const float* __restrict__ W, bf16_t* __restrict__ Wt,
    int K, int N, int Npad) {
  __shared__ float tile[64][65];
  const int kt = blockIdx.x * 64;
  const int nt = blockIdx.y * 64;
  const int r4 = threadIdx.x >> 6;
  const int c = threadIdx.x & 63;
#pragma unroll
  for (int i = 0; i < 16; i++) {
    int r = i * 4 + r4;
    int gn = nt + c;
    tile[r][c] = (gn < N) ? W[(size_t)(kt + r) * N + gn] : 0.0f;
  }
  __syncthreads();
#pragma unroll
  for (int i = 0; i < 16; i++) {
    int r = i * 4 + r4;
    Wt[(size_t)(nt + r) * K + kt + c] = (bf16_t)tile[c][r];
  }
}

// W3 (1024,1472) -> Wt3p (1536,1024) bf16, cols regrouped per-dim with pad:
// padded col n' = d*24 + p (p<23 real, p==23 zero). grid (16, 24).
__global__ __launch_bounds__(256) void transpose_w3p(
    const float* __restrict__ W3, bf16_t* __restrict__ Wt) {
  __shared__ float tile[64][65];
  const int kt = blockIdx.x * 64;
  const int nt = blockIdx.y * 64;
  const int r4 = threadIdx.x >> 6;
  const int c = threadIdx.x & 63;
  const int np = nt + c;
  const int d = np / 24, p = np % 24;
#pragma unroll
  for (int i = 0; i < 16; i++) {
    int r = i * 4 + r4;
    tile[r][c] = (p < 23) ? W3[(size_t)(kt + r) * 1472 + d * 23 + p] : 0.0f;
  }
  __syncthreads();
#pragma unroll
  for (int i = 0; i < 16; i++) {
    int r = i * 4 + r4;
    Wt[(size_t)(nt + r) * 1024 + kt + c] = (bf16_t)tile[c][r];
  }
}

// b3 -> 24-stride padded copy. grid (6,256).
__global__ __launch_bounds__(256) void prep_b3(const float* __restrict__ b3,
                                               float* __restrict__ b3p) {
  int t = blockIdx.x * 256 + threadIdx.x;
  if (t < 1536) {
    int d = t / 24, p = t % 24;
    b3p[t] = (p < 23) ? b3[d * 23 + p] : 0.0f;
  }
}

// ---------------------------------------------------------------------------
__global__ __launch_bounds__(256) void build_x(
    const float* __restrict__ x1, const float* __restrict__ mask1,
    const float* __restrict__ ctx, bf16_t* __restrict__ X, int boff) {
  int idx = blockIdx.x * 256 + threadIdx.x;
  int bl = idx >> 8;
  int c = idx & 255;
  size_t b = (size_t)(boff + bl);
  float v;
  if (c < 64)       v = x1[b * 64 + c];
  else if (c < 128) v = mask1[b * 64 + (c - 64)];
  else              v = ctx[b * 128 + (c - 128)];
  X[(size_t)bl * 256 + c] = (bf16_t)v;
}

// ---------------------------------------------------------------------------
// GEMM body v2: 128x128 tile, 4 waves 2x2, 4x4 frags of 16x16x32 MFMA.
// A: global_load_lds staging (two BK=32 halves per barrier pair).
// B: fragments loaded DIRECTLY from global (L2-hot weights) into VGPRs —
//    no Bs LDS buffer, no Bs ds_reads. LDS = 16 KB.
template <int RELU>
__device__ __forceinline__ void gemm_body(
    const bf16_t* __restrict__ A, const bf16_t* __restrict__ Bt,
    const float* __restrict__ bias, bf16_t* __restrict__ Cout, int N, int K) {
  __shared__ __align__(16) bf16_t As[2][128 * 32];
  const int tid = threadIdx.x;
  const int w = tid >> 6;
  const int lane = tid & 63;
  const int m0 = blockIdx.y * 128;
  const int n0 = blockIdx.x * 128;
  const int wm = (w & 1) * 64;
  const int wn = (w >> 1) * 64;
  const int lrow = lane & 15;
  const int quad = lane >> 4;

  f32x4 acc[4][4];
#pragma unroll
  for (int i = 0; i < 4; i++)
#pragma unroll
    for (int j = 0; j < 4; j++) acc[i][j] = (f32x4){0.f, 0.f, 0.f, 0.f};

  // Per-thread B row pointers (row fixed; k advances).
  const bf16_t* brow[4];
#pragma unroll
  for (int j = 0; j < 4; j++)
    brow[j] = Bt + (size_t)(n0 + wn + j * 16 + lrow) * K + quad * 8;

  const int nPair = K >> 6;
  for (int kp = 0; kp < nPair; kp++) {
    // Stage A (both 32-K halves), 2 chunks per wave per half.
#pragma unroll
    for (int h = 0; h < 2; h++) {
      const int k0 = (kp << 6) + (h << 5);
#pragma unroll
      for (int c = 0; c < 2; c++) {
        const int chunk = w * 2 + c;
        const int byteoff = (chunk << 10) + lane * 16;
        const int row = byteoff >> 6;
        const int kel = (byteoff & 63) >> 1;
        GLOAD_LDS16(A + (size_t)(m0 + row) * K + (k0 + kel),
                    As[h] + chunk * 512);
      }
    }
    // B fragments direct from global (complete during the barrier drain).
    bf16x8 bfr[2][4];
#pragma unroll
    for (int h = 0; h < 2; h++)
#pragma unroll
      for (int j = 0; j < 4; j++)
        bfr[h][j] = *(const bf16x8*)(brow[j] + (kp << 6) + (h << 5));
    __syncthreads();
#pragma unroll
    for (int h = 0; h < 2; h++) {
      bf16x8 af[4];
#pragma unroll
      for (int i = 0; i < 4; i++)
        af[i] = *(const bf16x8*)(As[h] + (wm + i * 16 + lrow) * 32 + quad * 8);
#pragma unroll
      for (int i = 0; i < 4; i++)
#pragma unroll
        for (int j = 0; j < 4; j++)
          acc[i][j] = __builtin_amdgcn_mfma_f32_16x16x32_bf16(
              af[i], bfr[h][j], acc[i][j], 0, 0, 0);
    }
    __syncthreads();
  }

  // C/D layout (m89/m91): col = lane&15, row = quad*4 + reg.
  float bv[4];
#pragma unroll
  for (int j = 0; j < 4; j++) bv[j] = bias[n0 + wn + j * 16 + lrow];
#pragma unroll
  for (int i = 0; i < 4; i++) {
    int rbase = m0 + wm + i * 16 + quad * 4;
#pragma unroll
    for (int j = 0; j < 4; j++) {
      int col = n0 + wn + j * 16 + lrow;
#pragma unroll
      for (int r = 0; r < 4; r++) {
        float v = acc[i][j][r] + bv[j];
        if (RELU) v = fmaxf(v, 0.0f);
        Cout[(size_t)(rbase + r) * N + col] = (bf16_t)v;
      }
    }
  }
}

__global__ __launch_bounds__(256) void gemm_bt(
    const bf16_t* __restrict__ A, const bf16_t* __restrict__ Bt,
    const float* __restrict__ bias, bf16_t* __restrict__ Cout, int N, int K) {
  gemm_body<1>(A, Bt, bias, Cout, N, K);
}

__global__ __launch_bounds__(256) void gemm4(
    const bf16_t* __restrict__ A, const bf16_t* __restrict__ Bt,
    const float* __restrict__ b3p, bf16_t* __restrict__ P, int K) {
  gemm_body<0>(A, Bt, b3p, P, 1536, K);
}

// ---------------------------------------------------------------------------
// RQ spline. Block = 8 batch rows. Stage 8x1536 bf16 from P (coalesced 16B
// loads), convert to fp32 into LDS at stride-25 per dim (odd stride ->
// conflict-free reads). Thread t: row = t>>5, dims t&31 and +32.
__global__ __launch_bounds__(256) void spline_kernel(
    const bf16_t* __restrict__ P, const float* __restrict__ x2,
    float* __restrict__ z_out, float* __restrict__ ld_out, int boff) {
  __shared__ float Pl[8 * 1600];
  const int tid = threadIdx.x;
  const int r0 = blockIdx.x * 8;

#pragma unroll
  for (int i = 0; i < 6; i++) {
    int idx = tid + i * 256;            // 0..1535
    int row = idx / 192;
    int rem = idx - row * 192;          // 16B chunk within row
    int d = rem / 3;
    int q = rem - d * 3;
    bf16x8 v = *(const bf16x8*)(P + (size_t)(r0 + row) * 1536 + rem * 8);
    float* dst = Pl + row * 1600 + d * 25 + q * 8;
#pragma unroll
    for (int j = 0; j < 8; j++) dst[j] = (float)v[j];
  }
  __syncthreads();

  const int row = tid >> 5;
  const int d0 = tid & 31;
  const size_t bg = (size_t)(boff + r0 + row);

  const float SHIFT = 0.54132485f;     // log(e-1)
  const float SHIFT_DX = 5.1944682f;   // log(exp(6.0-0.8)-1)
  const float left = -3.0f;
  const float delta_x = 0.8f + log1pf(expf(SHIFT_DX));
  const float right = left + delta_x;
  const float scale = delta_x;

  float ldsum = 0.0f;
#pragma unroll
  for (int dd = 0; dd < 2; dd++) {
    const int d = d0 + dd * 32;
    const float* pr = Pl + row * 1600 + d * 25;
    const float x = x2[bg * 64 + d];

    float mw = pr[0];
#pragma unroll
    for (int j = 1; j < 8; j++) mw = fmaxf(mw, pr[j]);
    float ew[8], sw = 0.f;
#pragma unroll
    for (int j = 0; j < 8; j++) { ew[j] = expf(pr[j] - mw); sw += ew[j]; }
    float invw = 1.0f / sw;
    float cw[9];
    cw[0] = left;
    float cum = 0.f;
#pragma unroll
    for (int j = 0; j < 8; j++) {
      cum += 0.1f + 0.2f * ew[j] * invw;
      cw[j + 1] = left + scale * cum;
    }
    float mh = pr[8];
#pragma unroll
    for (int j = 9; j < 16; j++) mh = fmaxf(mh, pr[j]);
    float eh[8], sh = 0.f;
#pragma unroll
    for (int j = 0; j < 8; j++) { eh[j] = expf(pr[8 + j] - mh); sh += eh[j]; }
    float invh = 1.0f / sh;
    float chh[9];
    chh[0] = left;
    float cumh = 0.f;
#pragma unroll
    for (int j = 0; j < 8; j++) {
      cumh += 0.1f + 0.2f * eh[j] * invh;
      chh[j + 1] = left + scale * cumh;
    }
    float dv[9];
    dv[0] = 1.0f;
    dv[8] = 1.0f;
#pragma unroll
    for (int j = 0; j < 7; j++) {
      float v = pr[16 + j] + SHIFT;
      dv[j + 1] = 0.001f + ((v > 20.f) ? v : log1pf(expf(v)));
    }
    int cnt = 0;
#pragma unroll
    for (int j = 0; j < 8; j++) cnt += (cw[j] <= x) ? 1 : 0;
    cnt += ((cw[8] + 1e-6f) <= x) ? 1 : 0;
    int idx = cnt - 1;
    idx = idx < 0 ? 0 : (idx > 7 ? 7 : idx);
    float x_k = cw[0], x_k1 = cw[1], y_k = chh[0], y_k1 = chh[1];
    float d0v = dv[0], d1v = dv[1];
#pragma unroll
    for (int j = 1; j < 8; j++) {
      bool s = (idx == j);
      x_k = s ? cw[j] : x_k;
      x_k1 = s ? cw[j + 1] : x_k1;
      y_k = s ? chh[j] : y_k;
      y_k1 = s ? chh[j + 1] : y_k1;
      d0v = s ? dv[j] : d0v;
      d1v = s ? dv[j + 1] : d1v;
    }
    float x_kd = x_k1 - x_k;
    float y_kd = y_k1 - y_k;
    float s_k = y_kd / x_kd;
    float xi = (x - x_k) / x_kd;
    float xi1m = xi * (1.f - xi);
    float alpha_k = y_kd * (s_k * xi * xi + d0v * xi1m);
    float beta_k = s_k + (d1v + d0v - 2.f * s_k) * xi1m;
    float z_sp = y_k + alpha_k / fmaxf(beta_k, 1e-8f);
    float oxi = 1.f - xi;
    float num = s_k * s_k * (d1v * xi * xi + 2.f * s_k * xi1m + d0v * oxi * oxi);
    float ld_sp = logf(fmaxf(num, 1e-8f)) - 2.f * logf(fmaxf(beta_k, 1e-8f));

    bool inside = (left <= x) && (x < right);
    float z = inside ? z_sp : x;
    float ld = inside ? ld_sp : 0.f;
    z_out[bg * 64 + d] = z;
    ldsum += ld;
  }
#pragma unroll
  for (int off = 16; off > 0; off >>= 1) ldsum += __shfl_down(ldsum, off, 32);
  if (d0 == 0) ld_out[bg] = ldsum;
}

// ---------------------------------------------------------------------------
extern "C" void kernel_launch(void* const* d_in, const int* in_sizes, int n_in,
                              void* d_out, int out_size, void* d_ws,
                              size_t ws_size, hipStream_t stream) {
  const float* x1 = (const float*)d_in[0];
  const float* x2 = (const float*)d_in[1];
  const float* ctx = (const float*)d_in[2];
  const float* mask1 = (const float*)d_in[3];
  const float* W0 = (const float*)d_in[4];
  const float* b0 = (const float*)d_in[5];
  const float* W1 = (const float*)d_in[6];
  const float* b1 = (const float*)d_in[7];
  const float* W2 = (const float*)d_in[8];
  const float* b2 = (const float*)d_in[9];
  const float* W3 = (const float*)d_in[10];
  const float* b3 = (const float*)d_in[11];
  float* out = (float*)d_out;

  const int B = 65536;
  char* ws = (char*)d_ws;

  bf16_t* Wt0 = (bf16_t*)ws;                           // 1024x256  (512 KB)
  bf16_t* Wt1 = (bf16_t*)(ws + 524288);                // 1024x1024 (2 MB)
  bf16_t* Wt2 = (bf16_t*)(ws + 524288 + 2097152);      // 1024x1024 (2 MB)
  bf16_t* Wt3 = (bf16_t*)(ws + 524288 + 2 * 2097152);  // 1536x1024 (3 MB)
  float* b3p = (float*)(ws + 524288 + 2 * 2097152 + 3145728);  // 6 KB
  const size_t wend = 524288 + 2 * 2097152 + 3145728 + 8192;

  // Adaptive chunking. Per-row: HA 2048 B + aliased region 3072 B
  // (X 512 / HB 2048 / P bf16 3072 — lifetimes disjoint).
  int C = 4;
  if (wend + (size_t)B * 5120 <= ws_size) C = 1;
  else if (wend + (size_t)(B / 2) * 5120 <= ws_size) C = 2;
  const int Bc = B / C;
  bf16_t* HA = (bf16_t*)(ws + wend);
  char* R = ws + wend + (size_t)Bc * 2048;
  bf16_t* X = (bf16_t*)R;
  bf16_t* HB = (bf16_t*)R;
  bf16_t* P = (bf16_t*)R;
  float* ld_out = out + (size_t)B * 64;

  transpose_w<<<dim3(4, 16), 256, 0, stream>>>(W0, Wt0, 256, 1024, 1024);
  transpose_w<<<dim3(16, 16), 256, 0, stream>>>(W1, Wt1, 1024, 1024, 1024);
  transpose_w<<<dim3(16, 16), 256, 0, stream>>>(W2, Wt2, 1024, 1024, 1024);
  transpose_w3p<<<dim3(16, 24), 256, 0, stream>>>(W3, Wt3);
  prep_b3<<<6, 256, 0, stream>>>(b3, b3p);

  for (int c = 0; c < C; c++) {
    const int boff = c * Bc;
    build_x<<<Bc, 256, 0, stream>>>(x1, mask1, ctx, X, boff);
    gemm_bt<<<dim3(8, Bc / 128), 256, 0, stream>>>(X, Wt0, b0, HA, 1024, 256);
    gemm_bt<<<dim3(8, Bc / 128), 256, 0, stream>>>(HA, Wt1, b1, HB, 1024, 1024);
    gemm_bt<<<dim3(8, Bc / 128), 256, 0, stream>>>(HB, Wt2, b2, HA, 1024, 1024);
    gemm4<<<dim3(12, Bc / 128), 256, 0, stream>>>(HA, Wt3, b3p, P, 1024);
    spline_kernel<<<Bc / 8, 256, 0, stream>>>(P, x2, out, ld_out, boff);
  }
}

// Round 7
// 1149.917 us; speedup vs baseline: 1.2773x; 1.2773x over previous
//
#include <hip/hip_runtime.h>

// RationalQuadratic: 4-layer MLP conditioner (bf16 MFMA GEMMs) + RQ spline.
// R7: R5 structure (R6's direct-global-B reverted: it re-fetched B from HBM
// +146MB/dispatch and stalled MFMA) + LDS bank swizzle. Fragment ds_read_b128
// at row*64B+quad*16B aliased ~8-way (6.29M conflict cyc/dispatch, +4cyc/read).
// Swizzle: LDS slot (row,quad) holds global k-chunk quad^((row>>1)&3) —
// applied by redirecting the GLOBAL source at stage time (LDS dest must stay
// base+lane*16 for global_load_lds); readers XOR the same way. 16-lane phase
// then covers all 32 banks (2-way = free, m136).

typedef __bf16 bf16_t;
typedef __bf16 bf16x8 __attribute__((ext_vector_type(8)));
typedef float f32x4 __attribute__((ext_vector_type(4)));

#define GLOAD_LDS16(g, l)                                               \
  __builtin_amdgcn_global_load_lds(                                     \
      (const __attribute__((address_space(1))) void*)(g),               \
      (__attribute__((address_space(3))) void*)(l), 16, 0, 0)

// ---------------------------------------------------------------------------
// W (K,N) fp32 row-major -> Wt (Npad,K) bf16 row-major. grid (K/64, Npad/64).
__global__ __launch_bounds__(256) void transpose_w(
    const float* __restrict__ W, bf16_t* __restrict__ Wt,
    int K, int N, int Npad) {
  __shared__ float tile[64][65];
  const int kt = blockIdx.x * 64;
  const int nt = blockIdx.y * 64;
  const int r4 = threadIdx.x >> 6;
  const int c = threadIdx.x & 63;
#pragma unroll
  for (int i = 0; i < 16; i++) {
    int r = i * 4 + r4;
    int gn = nt + c;
    tile[r][c] = (gn < N) ? W[(size_t)(kt + r) * N + gn] : 0.0f;
  }
  __syncthreads();
#pragma unroll
  for (int i = 0; i < 16; i++) {
    int r = i * 4 + r4;
    Wt[(size_t)(nt + r) * K + kt + c] = (bf16_t)tile[c][r];
  }
}

// W3 (1024,1472) -> Wt3p (1536,1024) bf16, cols regrouped per-dim with pad:
// padded col n' = d*24 + p (p<23 real, p==23 zero). grid (16, 24).
__global__ __launch_bounds__(256) void transpose_w3p(
    const float* __restrict__ W3, bf16_t* __restrict__ Wt) {
  __shared__ float tile[64][65];
  const int kt = blockIdx.x * 64;
  const int nt = blockIdx.y * 64;
  const int r4 = threadIdx.x >> 6;
  const int c = threadIdx.x & 63;
  const int np = nt + c;
  const int d = np / 24, p = np % 24;
#pragma unroll
  for (int i = 0; i < 16; i++) {
    int r = i * 4 + r4;
    tile[r][c] = (p < 23) ? W3[(size_t)(kt + r) * 1472 + d * 23 + p] : 0.0f;
  }
  __syncthreads();
#pragma unroll
  for (int i = 0; i < 16; i++) {
    int r = i * 4 + r4;
    Wt[(size_t)(nt + r) * 1024 + kt + c] = (bf16_t)tile[c][r];
  }
}

// b3 -> 24-stride padded copy. grid (6,256).
__global__ __launch_bounds__(256) void prep_b3(const float* __restrict__ b3,
                                               float* __restrict__ b3p) {
  int t = blockIdx.x * 256 + threadIdx.x;
  if (t < 1536) {
    int d = t / 24, p = t % 24;
    b3p[t] = (p < 23) ? b3[d * 23 + p] : 0.0f;
  }
}

// ---------------------------------------------------------------------------
__global__ __launch_bounds__(256) void build_x(
    const float* __restrict__ x1, const float* __restrict__ mask1,
    const float* __restrict__ ctx, bf16_t* __restrict__ X, int boff) {
  int idx = blockIdx.x * 256 + threadIdx.x;
  int bl = idx >> 8;
  int c = idx & 255;
  size_t b = (size_t)(boff + bl);
  float v;
  if (c < 64)       v = x1[b * 64 + c];
  else if (c < 128) v = mask1[b * 64 + (c - 64)];
  else              v = ctx[b * 128 + (c - 128)];
  X[(size_t)bl * 256 + c] = (bf16_t)v;
}

// ---------------------------------------------------------------------------
// GEMM body: 128x128 tile, 4 waves 2x2, 4x4 frags of 16x16x32 MFMA.
// Two BK=32 K-tiles per barrier pair (R4). Bank-swizzled LDS layout (R7):
// LDS (row, quad) holds global k-chunk (quad ^ ((row>>1)&3)).
template <int RELU>
__device__ __forceinline__ void gemm_body(
    const bf16_t* __restrict__ A, const bf16_t* __restrict__ Bt,
    const float* __restrict__ bias, bf16_t* __restrict__ Cout, int N, int K) {
  __shared__ __align__(16) bf16_t As[2][128 * 32];
  __shared__ __align__(16) bf16_t Bs[2][128 * 32];
  const int tid = threadIdx.x;
  const int w = tid >> 6;
  const int lane = tid & 63;
  const int m0 = blockIdx.y * 128;
  const int n0 = blockIdx.x * 128;
  const int wm = (w & 1) * 64;
  const int wn = (w >> 1) * 64;
  const int lrow = lane & 15;
  const int quad = lane >> 4;

  f32x4 acc[4][4];
#pragma unroll
  for (int i = 0; i < 4; i++)
#pragma unroll
    for (int j = 0; j < 4; j++) acc[i][j] = (f32x4){0.f, 0.f, 0.f, 0.f};

  const int nPair = K >> 6;
  for (int kp = 0; kp < nPair; kp++) {
#pragma unroll
    for (int h = 0; h < 2; h++) {
      const int k0 = (kp << 6) + (h << 5);
#pragma unroll
      for (int c = 0; c < 2; c++) {
        const int chunk = w * 2 + c;
        const int byteoff = (chunk << 10) + lane * 16;
        const int row = byteoff >> 6;
        const int q = (byteoff >> 4) & 3;
        const int qs = q ^ ((row >> 1) & 3);  // swizzled global k-chunk
        const int kel = qs * 8;
        GLOAD_LDS16(A + (size_t)(m0 + row) * K + (k0 + kel),
                    As[h] + chunk * 512);
        GLOAD_LDS16(Bt + (size_t)(n0 + row) * K + (k0 + kel),
                    Bs[h] + chunk * 512);
      }
    }
    __syncthreads();
#pragma unroll
    for (int h = 0; h < 2; h++) {
      bf16x8 af[4], bfr[4];
#pragma unroll
      for (int i = 0; i < 4; i++) {
        const int row = wm + i * 16 + lrow;
        const int qs = quad ^ ((row >> 1) & 3);
        af[i] = *(const bf16x8*)(As[h] + row * 32 + qs * 8);
      }
#pragma unroll
      for (int j = 0; j < 4; j++) {
        const int row = wn + j * 16 + lrow;
        const int qs = quad ^ ((row >> 1) & 3);
        bfr[j] = *(const bf16x8*)(Bs[h] + row * 32 + qs * 8);
      }
#pragma unroll
      for (int i = 0; i < 4; i++)
#pragma unroll
        for (int j = 0; j < 4; j++)
          acc[i][j] = __builtin_amdgcn_mfma_f32_16x16x32_bf16(
              af[i], bfr[j], acc[i][j], 0, 0, 0);
    }
    __syncthreads();
  }

  // C/D layout (m89/m91): col = lane&15, row = quad*4 + reg.
  float bv[4];
#pragma unroll
  for (int j = 0; j < 4; j++) bv[j] = bias[n0 + wn + j * 16 + lrow];
#pragma unroll
  for (int i = 0; i < 4; i++) {
    int rbase = m0 + wm + i * 16 + quad * 4;
#pragma unroll
    for (int j = 0; j < 4; j++) {
      int col = n0 + wn + j * 16 + lrow;
#pragma unroll
      for (int r = 0; r < 4; r++) {
        float v = acc[i][j][r] + bv[j];
        if (RELU) v = fmaxf(v, 0.0f);
        Cout[(size_t)(rbase + r) * N + col] = (bf16_t)v;
      }
    }
  }
}

__global__ __launch_bounds__(256) void gemm_bt(
    const bf16_t* __restrict__ A, const bf16_t* __restrict__ Bt,
    const float* __restrict__ bias, bf16_t* __restrict__ Cout, int N, int K) {
  gemm_body<1>(A, Bt, bias, Cout, N, K);
}

__global__ __launch_bounds__(256) void gemm4(
    const bf16_t* __restrict__ A, const bf16_t* __restrict__ Bt,
    const float* __restrict__ b3p, bf16_t* __restrict__ P, int K) {
  gemm_body<0>(A, Bt, b3p, P, 1536, K);
}

// ---------------------------------------------------------------------------
// RQ spline. Block = 8 batch rows. Stage 8x1536 bf16 from P (coalesced 16B
// loads), convert to fp32 into LDS at stride-25 per dim (odd stride ->
// conflict-free reads). Thread t: row = t>>5, dims t&31 and +32.
__global__ __launch_bounds__(256) void spline_kernel(
    const bf16_t* __restrict__ P, const float* __restrict__ x2,
    float* __restrict__ z_out, float* __restrict__ ld_out, int boff) {
  __shared__ float Pl[8 * 1600];
  const int tid = threadIdx.x;
  const int r0 = blockIdx.x * 8;

#pragma unroll
  for (int i = 0; i < 6; i++) {
    int idx = tid + i * 256;            // 0..1535
    int row = idx / 192;
    int rem = idx - row * 192;          // 16B chunk within row
    int d = rem / 3;
    int q = rem - d * 3;
    bf16x8 v = *(const bf16x8*)(P + (size_t)(r0 + row) * 1536 + rem * 8);
    float* dst = Pl + row * 1600 + d * 25 + q * 8;
#pragma unroll
    for (int j = 0; j < 8; j++) dst[j] = (float)v[j];
  }
  __syncthreads();

  const int row = tid >> 5;
  const int d0 = tid & 31;
  const size_t bg = (size_t)(boff + r0 + row);

  const float SHIFT = 0.54132485f;     // log(e-1)
  const float SHIFT_DX = 5.1944682f;   // log(exp(6.0-0.8)-1)
  const float left = -3.0f;
  const float delta_x = 0.8f + log1pf(expf(SHIFT_DX));
  const float right = left + delta_x;
  const float scale = delta_x;

  float ldsum = 0.0f;
#pragma unroll
  for (int dd = 0; dd < 2; dd++) {
    const int d = d0 + dd * 32;
    const float* pr = Pl + row * 1600 + d * 25;
    const float x = x2[bg * 64 + d];

    float mw = pr[0];
#pragma unroll
    for (int j = 1; j < 8; j++) mw = fmaxf(mw, pr[j]);
    float ew[8], sw = 0.f;
#pragma unroll
    for (int j = 0; j < 8; j++) { ew[j] = expf(pr[j] - mw); sw += ew[j]; }
    float invw = 1.0f / sw;
    float cw[9];
    cw[0] = left;
    float cum = 0.f;
#pragma unroll
    for (int j = 0; j < 8; j++) {
      cum += 0.1f + 0.2f * ew[j] * invw;
      cw[j + 1] = left + scale * cum;
    }
    float mh = pr[8];
#pragma unroll
    for (int j = 9; j < 16; j++) mh = fmaxf(mh, pr[j]);
    float eh[8], sh = 0.f;
#pragma unroll
    for (int j = 0; j < 8; j++) { eh[j] = expf(pr[8 + j] - mh); sh += eh[j]; }
    float invh = 1.0f / sh;
    float chh[9];
    chh[0] = left;
    float cumh = 0.f;
#pragma unroll
    for (int j = 0; j < 8; j++) {
      cumh += 0.1f + 0.2f * eh[j] * invh;
      chh[j + 1] = left + scale * cumh;
    }
    float dv[9];
    dv[0] = 1.0f;
    dv[8] = 1.0f;
#pragma unroll
    for (int j = 0; j < 7; j++) {
      float v = pr[16 + j] + SHIFT;
      dv[j + 1] = 0.001f + ((v > 20.f) ? v : log1pf(expf(v)));
    }
    int cnt = 0;
#pragma unroll
    for (int j = 0; j < 8; j++) cnt += (cw[j] <= x) ? 1 : 0;
    cnt += ((cw[8] + 1e-6f) <= x) ? 1 : 0;
    int idx = cnt - 1;
    idx = idx < 0 ? 0 : (idx > 7 ? 7 : idx);
    float x_k = cw[0], x_k1 = cw[1], y_k = chh[0], y_k1 = chh[1];
    float d0v = dv[0], d1v = dv[1];
#pragma unroll
    for (int j = 1; j < 8; j++) {
      bool s = (idx == j);
      x_k = s ? cw[j] : x_k;
      x_k1 = s ? cw[j + 1] : x_k1;
      y_k = s ? chh[j] : y_k;
      y_k1 = s ? chh[j + 1] : y_k1;
      d0v = s ? dv[j] : d0v;
      d1v = s ? dv[j + 1] : d1v;
    }
    float x_kd = x_k1 - x_k;
    float y_kd = y_k1 - y_k;
    float s_k = y_kd / x_kd;
    float xi = (x - x_k) / x_kd;
    float xi1m = xi * (1.f - xi);
    float alpha_k = y_kd * (s_k * xi * xi + d0v * xi1m);
    float beta_k = s_k + (d1v + d0v - 2.f * s_k) * xi1m;
    float z_sp = y_k + alpha_k / fmaxf(beta_k, 1e-8f);
    float oxi = 1.f - xi;
    float num = s_k * s_k * (d1v * xi * xi + 2.f * s_k * xi1m + d0v * oxi * oxi);
    float ld_sp = logf(fmaxf(num, 1e-8f)) - 2.f * logf(fmaxf(beta_k, 1e-8f));

    bool inside = (left <= x) && (x < right);
    float z = inside ? z_sp : x;
    float ld = inside ? ld_sp : 0.f;
    z_out[bg * 64 + d] = z;
    ldsum += ld;
  }
#pragma unroll
  for (int off = 16; off > 0; off >>= 1) ldsum += __shfl_down(ldsum, off, 32);
  if (d0 == 0) ld_out[bg] = ldsum;
}

// ---------------------------------------------------------------------------
extern "C" void kernel_launch(void* const* d_in, const int* in_sizes, int n_in,
                              void* d_out, int out_size, void* d_ws,
                              size_t ws_size, hipStream_t stream) {
  const float* x1 = (const float*)d_in[0];
  const float* x2 = (const float*)d_in[1];
  const float* ctx = (const float*)d_in[2];
  const float* mask1 = (const float*)d_in[3];
  const float* W0 = (const float*)d_in[4];
  const float* b0 = (const float*)d_in[5];
  const float* W1 = (const float*)d_in[6];
  const float* b1 = (const float*)d_in[7];
  const float* W2 = (const float*)d_in[8];
  const float* b2 = (const float*)d_in[9];
  const float* W3 = (const float*)d_in[10];
  const float* b3 = (const float*)d_in[11];
  float* out = (float*)d_out;

  const int B = 65536;
  char* ws = (char*)d_ws;

  bf16_t* Wt0 = (bf16_t*)ws;                           // 1024x256  (512 KB)
  bf16_t* Wt1 = (bf16_t*)(ws + 524288);                // 1024x1024 (2 MB)
  bf16_t* Wt2 = (bf16_t*)(ws + 524288 + 2097152);      // 1024x1024 (2 MB)
  bf16_t* Wt3 = (bf16_t*)(ws + 524288 + 2 * 2097152);  // 1536x1024 (3 MB)
  float* b3p = (float*)(ws + 524288 + 2 * 2097152 + 3145728);  // 6 KB
  const size_t wend = 524288 + 2 * 2097152 + 3145728 + 8192;

  // C=4 chunks (R5 known-good). Per-row: HA 2048 B + aliased region 3072 B
  // (X 512 / HB 2048 / P bf16 3072 — lifetimes disjoint).
  const int C = 4;
  const int Bc = B / C;  // 16384
  bf16_t* HA = (bf16_t*)(ws + wend);
  char* R = ws + wend + (size_t)Bc * 2048;
  bf16_t* X = (bf16_t*)R;
  bf16_t* HB = (bf16_t*)R;
  bf16_t* P = (bf16_t*)R;
  float* ld_out = out + (size_t)B * 64;

  transpose_w<<<dim3(4, 16), 256, 0, stream>>>(W0, Wt0, 256, 1024, 1024);
  transpose_w<<<dim3(16, 16), 256, 0, stream>>>(W1, Wt1, 1024, 1024, 1024);
  transpose_w<<<dim3(16, 16), 256, 0, stream>>>(W2, Wt2, 1024, 1024, 1024);
  transpose_w3p<<<dim3(16, 24), 256, 0, stream>>>(W3, Wt3);
  prep_b3<<<6, 256, 0, stream>>>(b3, b3p);

  for (int c = 0; c < C; c++) {
    const int boff = c * Bc;
    build_x<<<Bc, 256, 0, stream>>>(x1, mask1, ctx, X, boff);
    gemm_bt<<<dim3(8, Bc / 128), 256, 0, stream>>>(X, Wt0, b0, HA, 1024, 256);
    gemm_bt<<<dim3(8, Bc / 128), 256, 0, stream>>>(HA, Wt1, b1, HB, 1024, 1024);
    gemm_bt<<<dim3(8, Bc / 128), 256, 0, stream>>>(HB, Wt2, b2, HA, 1024, 1024);
    gemm4<<<dim3(12, Bc / 128), 256, 0, stream>>>(HA, Wt3, b3p, P, 1024);
    spline_kernel<<<Bc / 8, 256, 0, stream>>>(P, x2, out, ld_out, boff);
  }
}

// Round 8
// 1031.152 us; speedup vs baseline: 1.4245x; 1.1152x over previous
//
#include <hip/hip_runtime.h>

// RationalQuadratic: 4-layer MLP conditioner (bf16 MFMA GEMMs) + RQ spline.
// R8: R7 (dual-K barrier pair + bank-swizzled LDS, conflicts=0) with C=1
// chunking. Evidence: per-FLOP rate at C=1 (R1 mids: 0.63 us/GF, A fetched
// exactly 1x) vs C=4 (R5/R7 gemm4: 1.40 us/GF, A re-fetched ~4x). C=1 also
// cuts 29 launches -> 11. ws need = 344 MB; R1 proved ws >= 712 MB.

typedef __bf16 bf16_t;
typedef __bf16 bf16x8 __attribute__((ext_vector_type(8)));
typedef float f32x4 __attribute__((ext_vector_type(4)));

#define GLOAD_LDS16(g, l)                                               \
  __builtin_amdgcn_global_load_lds(                                     \
      (const __attribute__((address_space(1))) void*)(g),               \
      (__attribute__((address_space(3))) void*)(l), 16, 0, 0)

// ---------------------------------------------------------------------------
// W (K,N) fp32 row-major -> Wt (Npad,K) bf16 row-major. grid (K/64, Npad/64).
__global__ __launch_bounds__(256) void transpose_w(
    const float* __restrict__ W, bf16_t* __restrict__ Wt,
    int K, int N, int Npad) {
  __shared__ float tile[64][65];
  const int kt = blockIdx.x * 64;
  const int nt = blockIdx.y * 64;
  const int r4 = threadIdx.x >> 6;
  const int c = threadIdx.x & 63;
#pragma unroll
  for (int i = 0; i < 16; i++) {
    int r = i * 4 + r4;
    int gn = nt + c;
    tile[r][c] = (gn < N) ? W[(size_t)(kt + r) * N + gn] : 0.0f;
  }
  __syncthreads();
#pragma unroll
  for (int i = 0; i < 16; i++) {
    int r = i * 4 + r4;
    Wt[(size_t)(nt + r) * K + kt + c] = (bf16_t)tile[c][r];
  }
}

// W3 (1024,1472) -> Wt3p (1536,1024) bf16, cols regrouped per-dim with pad:
// padded col n' = d*24 + p (p<23 real, p==23 zero). grid (16, 24).
__global__ __launch_bounds__(256) void transpose_w3p(
    const float* __restrict__ W3, bf16_t* __restrict__ Wt) {
  __shared__ float tile[64][65];
  const int kt = blockIdx.x * 64;
  const int nt = blockIdx.y * 64;
  const int r4 = threadIdx.x >> 6;
  const int c = threadIdx.x & 63;
  const int np = nt + c;
  const int d = np / 24, p = np % 24;
#pragma unroll
  for (int i = 0; i < 16; i++) {
    int r = i * 4 + r4;
    tile[r][c] = (p < 23) ? W3[(size_t)(kt + r) * 1472 + d * 23 + p] : 0.0f;
  }
  __syncthreads();
#pragma unroll
  for (int i = 0; i < 16; i++) {
    int r = i * 4 + r4;
    Wt[(size_t)(nt + r) * 1024 + kt + c] = (bf16_t)tile[c][r];
  }
}

// b3 -> 24-stride padded copy. grid (6,256).
__global__ __launch_bounds__(256) void prep_b3(const float* __restrict__ b3,
                                               float* __restrict__ b3p) {
  int t = blockIdx.x * 256 + threadIdx.x;
  if (t < 1536) {
    int d = t / 24, p = t % 24;
    b3p[t] = (p < 23) ? b3[d * 23 + p] : 0.0f;
  }
}

// ---------------------------------------------------------------------------
__global__ __launch_bounds__(256) void build_x(
    const float* __restrict__ x1, const float* __restrict__ mask1,
    const float* __restrict__ ctx, bf16_t* __restrict__ X, int boff) {
  int idx = blockIdx.x * 256 + threadIdx.x;
  int bl = idx >> 8;
  int c = idx & 255;
  size_t b = (size_t)(boff + bl);
  float v;
  if (c < 64)       v = x1[b * 64 + c];
  else if (c < 128) v = mask1[b * 64 + (c - 64)];
  else              v = ctx[b * 128 + (c - 128)];
  X[(size_t)bl * 256 + c] = (bf16_t)v;
}

// ---------------------------------------------------------------------------
// GEMM body: 128x128 tile, 4 waves 2x2, 4x4 frags of 16x16x32 MFMA.
// Two BK=32 K-tiles per barrier pair (R4). Bank-swizzled LDS layout (R7):
// LDS (row, quad) holds global k-chunk (quad ^ ((row>>1)&3)) — conflicts = 0.
template <int RELU>
__device__ __forceinline__ void gemm_body(
    const bf16_t* __restrict__ A, const bf16_t* __restrict__ Bt,
    const float* __restrict__ bias, bf16_t* __restrict__ Cout, int N, int K) {
  __shared__ __align__(16) bf16_t As[2][128 * 32];
  __shared__ __align__(16) bf16_t Bs[2][128 * 32];
  const int tid = threadIdx.x;
  const int w = tid >> 6;
  const int lane = tid & 63;
  const int m0 = blockIdx.y * 128;
  const int n0 = blockIdx.x * 128;
  const int wm = (w & 1) * 64;
  const int wn = (w >> 1) * 64;
  const int lrow = lane & 15;
  const int quad = lane >> 4;

  f32x4 acc[4][4];
#pragma unroll
  for (int i = 0; i < 4; i++)
#pragma unroll
    for (int j = 0; j < 4; j++) acc[i][j] = (f32x4){0.f, 0.f, 0.f, 0.f};

  const int nPair = K >> 6;
  for (int kp = 0; kp < nPair; kp++) {
#pragma unroll
    for (int h = 0; h < 2; h++) {
      const int k0 = (kp << 6) + (h << 5);
#pragma unroll
      for (int c = 0; c < 2; c++) {
        const int chunk = w * 2 + c;
        const int byteoff = (chunk << 10) + lane * 16;
        const int row = byteoff >> 6;
        const int q = (byteoff >> 4) & 3;
        const int qs = q ^ ((row >> 1) & 3);  // swizzled global k-chunk
        const int kel = qs * 8;
        GLOAD_LDS16(A + (size_t)(m0 + row) * K + (k0 + kel),
                    As[h] + chunk * 512);
        GLOAD_LDS16(Bt + (size_t)(n0 + row) * K + (k0 + kel),
                    Bs[h] + chunk * 512);
      }
    }
    __syncthreads();
#pragma unroll
    for (int h = 0; h < 2; h++) {
      bf16x8 af[4], bfr[4];
#pragma unroll
      for (int i = 0; i < 4; i++) {
        const int row = wm + i * 16 + lrow;
        const int qs = quad ^ ((row >> 1) & 3);
        af[i] = *(const bf16x8*)(As[h] + row * 32 + qs * 8);
      }
#pragma unroll
      for (int j = 0; j < 4; j++) {
        const int row = wn + j * 16 + lrow;
        const int qs = quad ^ ((row >> 1) & 3);
        bfr[j] = *(const bf16x8*)(Bs[h] + row * 32 + qs * 8);
      }
#pragma unroll
      for (int i = 0; i < 4; i++)
#pragma unroll
        for (int j = 0; j < 4; j++)
          acc[i][j] = __builtin_amdgcn_mfma_f32_16x16x32_bf16(
              af[i], bfr[j], acc[i][j], 0, 0, 0);
    }
    __syncthreads();
  }

  // C/D layout (m89/m91): col = lane&15, row = quad*4 + reg.
  float bv[4];
#pragma unroll
  for (int j = 0; j < 4; j++) bv[j] = bias[n0 + wn + j * 16 + lrow];
#pragma unroll
  for (int i = 0; i < 4; i++) {
    int rbase = m0 + wm + i * 16 + quad * 4;
#pragma unroll
    for (int j = 0; j < 4; j++) {
      int col = n0 + wn + j * 16 + lrow;
#pragma unroll
      for (int r = 0; r < 4; r++) {
        float v = acc[i][j][r] + bv[j];
        if (RELU) v = fmaxf(v, 0.0f);
        Cout[(size_t)(rbase + r) * N + col] = (bf16_t)v;
      }
    }
  }
}

__global__ __launch_bounds__(256) void gemm_bt(
    const bf16_t* __restrict__ A, const bf16_t* __restrict__ Bt,
    const float* __restrict__ bias, bf16_t* __restrict__ Cout, int N, int K) {
  gemm_body<1>(A, Bt, bias, Cout, N, K);
}

__global__ __launch_bounds__(256) void gemm4(
    const bf16_t* __restrict__ A, const bf16_t* __restrict__ Bt,
    const float* __restrict__ b3p, bf16_t* __restrict__ P, int K) {
  gemm_body<0>(A, Bt, b3p, P, 1536, K);
}

// ---------------------------------------------------------------------------
// RQ spline. Block = 8 batch rows. Stage 8x1536 bf16 from P (coalesced 16B
// loads), convert to fp32 into LDS at stride-25 per dim (odd stride ->
// conflict-free reads). Thread t: row = t>>5, dims t&31 and +32.
__global__ __launch_bounds__(256) void spline_kernel(
    const bf16_t* __restrict__ P, const float* __restrict__ x2,
    float* __restrict__ z_out, float* __restrict__ ld_out, int boff) {
  __shared__ float Pl[8 * 1600];
  const int tid = threadIdx.x;
  const int r0 = blockIdx.x * 8;

#pragma unroll
  for (int i = 0; i < 6; i++) {
    int idx = tid + i * 256;            // 0..1535
    int row = idx / 192;
    int rem = idx - row * 192;          // 16B chunk within row
    int d = rem / 3;
    int q = rem - d * 3;
    bf16x8 v = *(const bf16x8*)(P + (size_t)(r0 + row) * 1536 + rem * 8);
    float* dst = Pl + row * 1600 + d * 25 + q * 8;
#pragma unroll
    for (int j = 0; j < 8; j++) dst[j] = (float)v[j];
  }
  __syncthreads();

  const int row = tid >> 5;
  const int d0 = tid & 31;
  const size_t bg = (size_t)(boff + r0 + row);

  const float SHIFT = 0.54132485f;     // log(e-1)
  const float SHIFT_DX = 5.1944682f;   // log(exp(6.0-0.8)-1)
  const float left = -3.0f;
  const float delta_x = 0.8f + log1pf(expf(SHIFT_DX));
  const float right = left + delta_x;
  const float scale = delta_x;

  float ldsum = 0.0f;
#pragma unroll
  for (int dd = 0; dd < 2; dd++) {
    const int d = d0 + dd * 32;
    const float* pr = Pl + row * 1600 + d * 25;
    const float x = x2[bg * 64 + d];

    float mw = pr[0];
#pragma unroll
    for (int j = 1; j < 8; j++) mw = fmaxf(mw, pr[j]);
    float ew[8], sw = 0.f;
#pragma unroll
    for (int j = 0; j < 8; j++) { ew[j] = expf(pr[j] - mw); sw += ew[j]; }
    float invw = 1.0f / sw;
    float cw[9];
    cw[0] = left;
    float cum = 0.f;
#pragma unroll
    for (int j = 0; j < 8; j++) {
      cum += 0.1f + 0.2f * ew[j] * invw;
      cw[j + 1] = left + scale * cum;
    }
    float mh = pr[8];
#pragma unroll
    for (int j = 9; j < 16; j++) mh = fmaxf(mh, pr[j]);
    float eh[8], sh = 0.f;
#pragma unroll
    for (int j = 0; j < 8; j++) { eh[j] = expf(pr[8 + j] - mh); sh += eh[j]; }
    float invh = 1.0f / sh;
    float chh[9];
    chh[0] = left;
    float cumh = 0.f;
#pragma unroll
    for (int j = 0; j < 8; j++) {
      cumh += 0.1f + 0.2f * eh[j] * invh;
      chh[j + 1] = left + scale * cumh;
    }
    float dv[9];
    dv[0] = 1.0f;
    dv[8] = 1.0f;
#pragma unroll
    for (int j = 0; j < 7; j++) {
      float v = pr[16 + j] + SHIFT;
      dv[j + 1] = 0.001f + ((v > 20.f) ? v : log1pf(expf(v)));
    }
    int cnt = 0;
#pragma unroll
    for (int j = 0; j < 8; j++) cnt += (cw[j] <= x) ? 1 : 0;
    cnt += ((cw[8] + 1e-6f) <= x) ? 1 : 0;
    int idx = cnt - 1;
    idx = idx < 0 ? 0 : (idx > 7 ? 7 : idx);
    float x_k = cw[0], x_k1 = cw[1], y_k = chh[0], y_k1 = chh[1];
    float d0v = dv[0], d1v = dv[1];
#pragma unroll
    for (int j = 1; j < 8; j++) {
      bool s = (idx == j);
      x_k = s ? cw[j] : x_k;
      x_k1 = s ? cw[j + 1] : x_k1;
      y_k = s ? chh[j] : y_k;
      y_k1 = s ? chh[j + 1] : y_k1;
      d0v = s ? dv[j] : d0v;
      d1v = s ? dv[j + 1] : d1v;
    }
    float x_kd = x_k1 - x_k;
    float y_kd = y_k1 - y_k;
    float s_k = y_kd / x_kd;
    float xi = (x - x_k) / x_kd;
    float xi1m = xi * (1.f - xi);
    float alpha_k = y_kd * (s_k * xi * xi + d0v * xi1m);
    float beta_k = s_k + (d1v + d0v - 2.f * s_k) * xi1m;
    float z_sp = y_k + alpha_k / fmaxf(beta_k, 1e-8f);
    float oxi = 1.f - xi;
    float num = s_k * s_k * (d1v * xi * xi + 2.f * s_k * xi1m + d0v * oxi * oxi);
    float ld_sp = logf(fmaxf(num, 1e-8f)) - 2.f * logf(fmaxf(beta_k, 1e-8f));

    bool inside = (left <= x) && (x < right);
    float z = inside ? z_sp : x;
    float ld = inside ? ld_sp : 0.f;
    z_out[bg * 64 + d] = z;
    ldsum += ld;
  }
#pragma unroll
  for (int off = 16; off > 0; off >>= 1) ldsum += __shfl_down(ldsum, off, 32);
  if (d0 == 0) ld_out[bg] = ldsum;
}

// ---------------------------------------------------------------------------
extern "C" void kernel_launch(void* const* d_in, const int* in_sizes, int n_in,
                              void* d_out, int out_size, void* d_ws,
                              size_t ws_size, hipStream_t stream) {
  const float* x1 = (const float*)d_in[0];
  const float* x2 = (const float*)d_in[1];
  const float* ctx = (const float*)d_in[2];
  const float* mask1 = (const float*)d_in[3];
  const float* W0 = (const float*)d_in[4];
  const float* b0 = (const float*)d_in[5];
  const float* W1 = (const float*)d_in[6];
  const float* b1 = (const float*)d_in[7];
  const float* W2 = (const float*)d_in[8];
  const float* b2 = (const float*)d_in[9];
  const float* W3 = (const float*)d_in[10];
  const float* b3 = (const float*)d_in[11];
  float* out = (float*)d_out;

  const int B = 65536;
  char* ws = (char*)d_ws;

  bf16_t* Wt0 = (bf16_t*)ws;                           // 1024x256  (512 KB)
  bf16_t* Wt1 = (bf16_t*)(ws + 524288);                // 1024x1024 (2 MB)
  bf16_t* Wt2 = (bf16_t*)(ws + 524288 + 2097152);      // 1024x1024 (2 MB)
  bf16_t* Wt3 = (bf16_t*)(ws + 524288 + 2 * 2097152);  // 1536x1024 (3 MB)
  float* b3p = (float*)(ws + 524288 + 2 * 2097152 + 3145728);  // 6 KB
  const size_t wend = 524288 + 2 * 2097152 + 3145728 + 8192;

  // Adaptive chunking, prefer C=1. Per-row: HA 2048 B + aliased region 3072 B
  // (X 512 / HB 2048 / P bf16 3072 — lifetimes disjoint: X dies at g0, HB
  // dies at g2, P born at g4). C=1 needs wend + 336 MB; R1 proved ws >= 712MB.
  int C = 4;
  if (wend + (size_t)B * 5120 <= ws_size) C = 1;
  else if (wend + (size_t)(B / 2) * 5120 <= ws_size) C = 2;
  const int Bc = B / C;
  bf16_t* HA = (bf16_t*)(ws + wend);
  char* R = ws + wend + (size_t)Bc * 2048;
  bf16_t* X = (bf16_t*)R;
  bf16_t* HB = (bf16_t*)R;
  bf16_t* P = (bf16_t*)R;
  float* ld_out = out + (size_t)B * 64;

  transpose_w<<<dim3(4, 16), 256, 0, stream>>>(W0, Wt0, 256, 1024, 1024);
  transpose_w<<<dim3(16, 16), 256, 0, stream>>>(W1, Wt1, 1024, 1024, 1024);
  transpose_w<<<dim3(16, 16), 256, 0, stream>>>(W2, Wt2, 1024, 1024, 1024);
  transpose_w3p<<<dim3(16, 24), 256, 0, stream>>>(W3, Wt3);
  prep_b3<<<6, 256, 0, stream>>>(b3, b3p);

  for (int c = 0; c < C; c++) {
    const int boff = c * Bc;
    build_x<<<Bc, 256, 0, stream>>>(x1, mask1, ctx, X, boff);
    gemm_bt<<<dim3(8, Bc / 128), 256, 0, stream>>>(X, Wt0, b0, HA, 1024, 256);
    gemm_bt<<<dim3(8, Bc / 128), 256, 0, stream>>>(HA, Wt1, b1, HB, 1024, 1024);
    gemm_bt<<<dim3(8, Bc / 128), 256, 0, stream>>>(HB, Wt2, b2, HA, 1024, 1024);
    gemm4<<<dim3(12, Bc / 128), 256, 0, stream>>>(HA, Wt3, b3p, P, 1024);
    spline_kernel<<<Bc / 8, 256, 0, stream>>>(P, x2, out, ld_out, boff);
  }
}